// Round 9
// baseline (297.697 us; speedup 1.0000x reference)
//
#include <hip/hip_runtime.h>
#include <hip/hip_bf16.h>
#include <math.h>

#define BB 8
#define NN 2048
#define TN 4096
#define DD 64

typedef __attribute__((ext_vector_type(8))) short short8;
typedef __attribute__((ext_vector_type(4))) float f32x4;
typedef __attribute__((ext_vector_type(4))) unsigned int u32x4;

__device__ __forceinline__ unsigned short f2bf(float f) {
    union { float f; unsigned int i; } v; v.f = f;
    unsigned int r = v.i + 0x7FFF + ((v.i >> 16) & 1);   // RNE
    return (unsigned short)(r >> 16);
}

// K1: Wh = concat(ht,h) @ W (f32); s1 = Wh@a1, s2 = Wh@a2; exp tables.
// E1p/E1n planar (k4), E1i interleaved 16/row (k2 uniform loads), E2p/E2n planar.
__global__ void k1_wh(const float* __restrict__ h,
                      const float* __restrict__ ht,
                      const float* __restrict__ W,
                      const float* __restrict__ a1,
                      const float* __restrict__ a2,
                      float* __restrict__ Wh,
                      float* __restrict__ E1p, float* __restrict__ E1n,
                      float* __restrict__ E2p, float* __restrict__ E2n,
                      float* __restrict__ E1i) {
    int tid = threadIdx.x;
    int w = tid >> 6, l = tid & 63;
    int rowglob = blockIdx.x * 4 + w;          // b*TN + m
    int b = rowglob >> 12;
    int m = rowglob & (TN - 1);
    const float* src = (m < NN) ? (ht + ((size_t)b * NN + m) * DD)
                                : (h  + ((size_t)b * NN + (m - NN)) * DD);
    const f32x4* src4 = reinterpret_cast<const f32x4*>(src);
    float c0 = 0.f, c1 = 0.f, c2 = 0.f, c3 = 0.f;
    #pragma unroll
    for (int k = 0; k < 16; ++k) {
        f32x4 s = src4[k];                      // wave-uniform 16B broadcast
        c0 += s[0] * W[(k * 4 + 0) * 64 + l];
        c1 += s[1] * W[(k * 4 + 1) * 64 + l];
        c2 += s[2] * W[(k * 4 + 2) * 64 + l];
        c3 += s[3] * W[(k * 4 + 3) * 64 + l];
    }
    float acc = (c0 + c1) + (c2 + c3);
    Wh[((size_t)b * TN + m) * DD + l] = acc;
    float r1 = acc * a1[l];
    float r2 = acc * a2[l];
    #pragma unroll
    for (int off = 32; off > 0; off >>= 1) {
        r1 += __shfl_xor(r1, off, 64);
        r2 += __shfl_xor(r2, off, 64);
    }
    if (l == 0) {
        size_t o = (size_t)b * TN + m;
        float pp = __expf(r1), pn = __expf(0.2f * r1);
        E1p[o] = pp;
        E1n[o] = pn;
        // interleaved: [0..3]=p(b0..3) [4..7]=n(b0..3) [8..11]=p(b4..7) [12..15]=n(b4..7)
        int sp = (b < 4) ? b       : 8 + (b - 4);
        int sn = (b < 4) ? 4 + b   : 12 + (b - 4);
        E1i[(size_t)m * 16 + sp] = pp;
        E1i[(size_t)m * 16 + sn] = pn;
        E2p[o] = __expf(r2);
        E2n[o] = __expf(0.2f * r2);
    }
}

// K2 (fused mask+stats): one streaming pass over adj (64 MB).
// e1 via wave-uniform f32x4 loads (no LDS); masking via acc += v*av (adj in {0,1});
// packed-f32 math across 4-batch groups. grid (16 j-tiles x 64 i-strips).
__global__ __launch_bounds__(256) void k2_mask_stats(
    const float* __restrict__ adj,
    const float* __restrict__ E1i,
    const float* __restrict__ E2p, const float* __restrict__ E2n,
    unsigned long long* __restrict__ rowmask,
    float* __restrict__ Spart) {
    int tid = threadIdx.x;
    int w = tid >> 6, l = tid & 63;
    int j = blockIdx.x * 256 + tid;
    int i0 = blockIdx.y * 64;
    f32x4 e2p0, e2p1, e2n0, e2n1;
    #pragma unroll
    for (int b = 0; b < 4; ++b) {
        e2p0[b] = E2p[(size_t)b * TN + j];
        e2n0[b] = E2n[(size_t)b * TN + j];
        e2p1[b] = E2p[(size_t)(b + 4) * TN + j];
        e2n1[b] = E2n[(size_t)(b + 4) * TN + j];
    }
    f32x4 acc0 = {0.f, 0.f, 0.f, 0.f}, acc1 = {0.f, 0.f, 0.f, 0.f};
    const f32x4* e1 = reinterpret_cast<const f32x4*>(E1i + (size_t)i0 * 16);
    #pragma unroll 4
    for (int ii = 0; ii < 64; ++ii) {
        float av = adj[(size_t)(i0 + ii) * TN + j];     // coalesced 256B/wave
        unsigned long long bal = __ballot(av != 0.f);
        if (l == 0)
            rowmask[(size_t)(i0 + ii) * 64 + blockIdx.x * 4 + w] = bal;
        f32x4 P0 = e1[ii * 4 + 0];                      // wave-uniform loads
        f32x4 N0 = e1[ii * 4 + 1];
        f32x4 P1 = e1[ii * 4 + 2];
        f32x4 N1 = e1[ii * 4 + 3];
        f32x4 v0 = __builtin_elementwise_max(P0 * e2p0, N0 * e2n0);
        f32x4 v1 = __builtin_elementwise_max(P1 * e2p1, N1 * e2n1);
        acc0 += v0 * av;                                 // av in {0,1}: exact mask
        acc1 += v1 * av;
    }
    #pragma unroll
    for (int b = 0; b < 4; ++b) {
        Spart[((size_t)blockIdx.y * 8 + b) * TN + j]     = acc0[b];
        Spart[((size_t)blockIdx.y * 8 + b + 4) * TN + j] = acc1[b];
    }
}

// K3: reduce Spart -> 1/S, then Whn_t[b][d][j] = Wh[b][j][d]/S[b][j] (bf16 T)
__global__ __launch_bounds__(256) void k3_whn(
    const float* __restrict__ Wh,
    const float* __restrict__ Spart,
    unsigned short* __restrict__ Wt) {
    __shared__ float tile[64][65];
    __shared__ float ps[4][64];
    __shared__ float rs[64];
    int b = blockIdx.y;
    int j0 = blockIdx.x * 64;
    int tid = threadIdx.x;
    int jj = tid & 63, part = tid >> 6;
    float s = 0.f;
    #pragma unroll
    for (int k = 0; k < 16; ++k) {
        int is = part * 16 + k;
        s += Spart[((size_t)is * 8 + b) * TN + j0 + jj];
    }
    ps[part][jj] = s;
    __syncthreads();
    if (tid < 64) rs[tid] = 1.0f / (ps[0][tid] + ps[1][tid] + ps[2][tid] + ps[3][tid]);
    for (int e = tid; e < 4096; e += 256) {
        int jt = e >> 6, d = e & 63;
        tile[jt][d] = Wh[((size_t)b * TN + j0 + jt) * DD + d];
    }
    __syncthreads();
    for (int e = tid; e < 512; e += 256) {
        int d = e >> 3, jg = e & 7;
        union { unsigned short u[8]; short8 s8; } pk;
        #pragma unroll
        for (int k = 0; k < 8; ++k) {
            int jt = jg * 8 + k;
            pk.u[k] = f2bf(tile[jt][d] * rs[jt]);
        }
        *reinterpret_cast<short8*>(Wt + ((size_t)b * DD + d) * TN + j0 + jg * 8) = pk.s8;
    }
}

// K4: hp += sum_{j in quarter} P[i][j]*Whn[j][d]; P on the fly in MFMA A-layout.
// 256 thr (4 waves), i-tile 64, js=4 -> grid 2048 = 8 blocks/CU (LDS-capped).
// Single-buffer LDS B-tile (128j x 64d, stride 140: conflict-free), 2-barrier
// jt loop with register prefetch. js pairs share hp buffers via f32 atomicAdd.
__global__ __launch_bounds__(256, 8) void k4_pv(
    const unsigned int* __restrict__ rowmask32,
    const float* __restrict__ E1p, const float* __restrict__ E1n,
    const float* __restrict__ E2p, const float* __restrict__ E2n,
    const unsigned short* __restrict__ Wt,
    float* __restrict__ hp0, float* __restrict__ hp1) {
    __shared__ unsigned short wt_s[64 * 140];
    int bx = blockIdx.x;
    int b  = bx & 7;                 // XCD round-robin
    int js = (bx >> 3) & 3;
    int i0 = (bx >> 5) * 64;
    int tid = threadIdx.x;
    int w = tid >> 6, l = tid & 63;
    int m = l & 15, q = l >> 4;
    int irow = i0 + w * 16 + m;
    float e1p_v = E1p[(size_t)b * TN + irow];
    float e1n_v = E1n[(size_t)b * TN + irow];
    const float* e2pb = E2p + (size_t)b * TN;
    const float* e2nb = E2n + (size_t)b * TN;
    const unsigned short* wtb = Wt + (size_t)b * DD * TN;
    const unsigned int* mrow = rowmask32 + (size_t)irow * 128;

    int r0 = tid >> 4, c0 = tid & 15;
    const int jbase = js * 1024;

    f32x4 acc[4];
    #pragma unroll
    for (int dt = 0; dt < 4; ++dt) acc[dt] = (f32x4){0.f, 0.f, 0.f, 0.f};

    // prefetch tile jt=0
    short8 g[4];
    #pragma unroll
    for (int k = 0; k < 4; ++k)
        g[k] = *reinterpret_cast<const short8*>(
            wtb + (size_t)(r0 + 16 * k) * TN + jbase + c0 * 8);

    for (int jt = 0; jt < 8; ++jt) {
        int j0 = jbase + jt * 128;
        __syncthreads();                                  // prior reads done
        #pragma unroll
        for (int k = 0; k < 4; ++k)
            *reinterpret_cast<short8*>(&wt_s[(r0 + 16 * k) * 140 + c0 * 8]) = g[k];
        if (jt < 7) {                                     // prefetch next tile
            #pragma unroll
            for (int k = 0; k < 4; ++k)
                g[k] = *reinterpret_cast<const short8*>(
                    wtb + (size_t)(r0 + 16 * k) * TN + j0 + 128 + c0 * 8);
        }
        u32x4 m4 = *reinterpret_cast<const u32x4*>(mrow + (j0 >> 5));
        __syncthreads();                                  // tile visible

        #pragma unroll
        for (int t = 0; t < 4; ++t) {
            int jb = j0 + t * 32 + q * 8;
            unsigned int bytev = (m4[t] >> (q * 8)) & 0xFFu;
            f32x4 p20 = *reinterpret_cast<const f32x4*>(e2pb + jb);
            f32x4 p21 = *reinterpret_cast<const f32x4*>(e2pb + jb + 4);
            f32x4 n20 = *reinterpret_cast<const f32x4*>(e2nb + jb);
            f32x4 n21 = *reinterpret_cast<const f32x4*>(e2nb + jb + 4);
            f32x4 v0 = __builtin_elementwise_max(p20 * e1p_v, n20 * e1n_v);
            f32x4 v1 = __builtin_elementwise_max(p21 * e1p_v, n21 * e1n_v);
            union { f32x4 f; u32x4 u; } uv0, uv1;
            uv0.f = v0; uv1.f = v1;
            u32x4 mk0, mk1;
            #pragma unroll
            for (int c = 0; c < 4; ++c) {
                mk0[c] = (unsigned int)((int)(bytev << (31 - c)) >> 31);
                mk1[c] = (unsigned int)((int)(bytev << (27 - c)) >> 31);
            }
            uv0.u &= mk0; uv1.u &= mk1;
            union { unsigned int u[4]; short8 s8; } af;
            __hip_bfloat162 hb0 = __float22bfloat162_rn(make_float2(uv0.f[0], uv0.f[1]));
            __hip_bfloat162 hb1 = __float22bfloat162_rn(make_float2(uv0.f[2], uv0.f[3]));
            __hip_bfloat162 hb2 = __float22bfloat162_rn(make_float2(uv1.f[0], uv1.f[1]));
            __hip_bfloat162 hb3 = __float22bfloat162_rn(make_float2(uv1.f[2], uv1.f[3]));
            af.u[0] = *reinterpret_cast<unsigned int*>(&hb0);
            af.u[1] = *reinterpret_cast<unsigned int*>(&hb1);
            af.u[2] = *reinterpret_cast<unsigned int*>(&hb2);
            af.u[3] = *reinterpret_cast<unsigned int*>(&hb3);
            #pragma unroll
            for (int dt = 0; dt < 4; ++dt) {
                short8 bf = *reinterpret_cast<const short8*>(
                    &wt_s[(dt * 16 + m) * 140 + t * 32 + q * 8]);
                acc[dt] = __builtin_amdgcn_mfma_f32_16x16x32_bf16(af.s8, bf, acc[dt], 0, 0, 0);
            }
        }
    }

    // C row = q*4+r, col = dt*16+m; js pair shares a buffer via atomicAdd
    float* hp = (js < 2) ? hp0 : hp1;
    int gbase = i0 + w * 16 + q * 4;
    #pragma unroll
    for (int dt = 0; dt < 4; ++dt) {
        int d = dt * 16 + m;
        #pragma unroll
        for (int r = 0; r < 4; ++r) {
            int g2 = gbase + r;
            atomicAdd(&hp[((size_t)b * TN + g2) * DD + d], acc[dt][r]);
        }
    }
}

// K5: out = elu(hp0 + hp1) with concat remap; float4
__global__ void k5_epi(const float* __restrict__ hp0,
                       const float* __restrict__ hp1,
                       float* __restrict__ out) {
    int t = blockIdx.x * 256 + threadIdx.x;       // < 524288
    int d4 = t & 31;
    int n = (t >> 5) & 2047;
    int b = t >> 16;
    int g, sd;
    if (d4 < 16) { g = n;        sd = d4 * 4; }
    else         { g = n + NN;   sd = (d4 - 16) * 4; }
    size_t off = ((size_t)b * TN + g) * DD + sd;
    f32x4 v0 = *reinterpret_cast<const f32x4*>(hp0 + off);
    f32x4 v1 = *reinterpret_cast<const f32x4*>(hp1 + off);
    f32x4 r;
    #pragma unroll
    for (int c = 0; c < 4; ++c) {
        float v = v0[c] + v1[c];
        r[c] = (v > 0.f) ? v : expm1f(v);
    }
    *reinterpret_cast<f32x4*>(out + ((size_t)b * NN + n) * 128 + d4 * 4) = r;
}

extern "C" void kernel_launch(void* const* d_in, const int* in_sizes, int n_in,
                              void* d_out, int out_size, void* d_ws, size_t ws_size,
                              hipStream_t stream) {
    const float* h   = (const float*)d_in[0];
    const float* ht  = (const float*)d_in[1];
    const float* W   = (const float*)d_in[2];
    const float* a1  = (const float*)d_in[3];
    const float* a2  = (const float*)d_in[4];
    const float* adj = (const float*)d_in[5];
    float* out = (float*)d_out;

    char* ws = (char*)d_ws;
    float* Wh          = (float*)(ws);                       // 8 MB (-> hp0)
    float* Spart       = (float*)(ws + (8 << 20));           // 8 MB (-> hp1)
    unsigned short* Wt = (unsigned short*)(ws + (16 << 20)); // 4 MB
    float* E1p         = (float*)(ws + (20 << 20));
    float* E1n         = (float*)(ws + (20 << 20) + (128 << 10));
    float* E2p         = (float*)(ws + (20 << 20) + (256 << 10));
    float* E2n         = (float*)(ws + (20 << 20) + (384 << 10));
    unsigned long long* rowmask = (unsigned long long*)(ws + (20 << 20) + (512 << 10)); // 2 MB
    float* E1i         = (float*)(ws + (20 << 20) + (512 << 10) + (2 << 20)); // 256 KB
    const unsigned int* rowmask32 = (const unsigned int*)rowmask;
    float* hp0 = Wh;      // dead after k3
    float* hp1 = Spart;   // dead after k3

    k1_wh<<<dim3(BB * TN / 4), dim3(256), 0, stream>>>(h, ht, W, a1, a2, Wh,
                                                       E1p, E1n, E2p, E2n, E1i);
    k2_mask_stats<<<dim3(16, 64), dim3(256), 0, stream>>>(adj, E1i, E2p, E2n,
                                                          rowmask, Spart);
    k3_whn<<<dim3(64, 8), dim3(256), 0, stream>>>(Wh, Spart, Wt);
    hipMemsetAsync(hp0, 0, (size_t)BB * TN * DD * sizeof(float), stream);
    hipMemsetAsync(hp1, 0, (size_t)BB * TN * DD * sizeof(float), stream);
    k4_pv<<<dim3(2048), dim3(256), 0, stream>>>(rowmask32, E1p, E1n, E2p, E2n, Wt,
                                                hp0, hp1);
    k5_epi<<<dim3(2048), dim3(256), 0, stream>>>(hp0, hp1, out);
}

// Round 10
// 284.041 us; speedup vs baseline: 1.0481x; 1.0481x over previous
//
#include <hip/hip_runtime.h>
#include <hip/hip_bf16.h>
#include <math.h>

#define BB 8
#define NN 2048
#define TN 4096
#define DD 64

typedef __attribute__((ext_vector_type(8))) short short8;
typedef __attribute__((ext_vector_type(4))) float f32x4;
typedef __attribute__((ext_vector_type(4))) unsigned int u32x4;
typedef __attribute__((ext_vector_type(4))) unsigned short u16x4;

__device__ __forceinline__ unsigned short f2bf(float f) {
    union { float f; unsigned int i; } v; v.f = f;
    unsigned int r = v.i + 0x7FFF + ((v.i >> 16) & 1);   // RNE
    return (unsigned short)(r >> 16);
}
__device__ __forceinline__ float bf2f(unsigned short u) {
    union { unsigned int i; float f; } v; v.i = ((unsigned int)u) << 16; return v.f;
}

// K1: Wh = concat(ht,h) @ W (f32); s1 = Wh@a1, s2 = Wh@a2; exp tables.
// E1p/E1n planar (k4), E1i interleaved 16/row (k2 uniform loads), E2p/E2n planar.
__global__ void k1_wh(const float* __restrict__ h,
                      const float* __restrict__ ht,
                      const float* __restrict__ W,
                      const float* __restrict__ a1,
                      const float* __restrict__ a2,
                      float* __restrict__ Wh,
                      float* __restrict__ E1p, float* __restrict__ E1n,
                      float* __restrict__ E2p, float* __restrict__ E2n,
                      float* __restrict__ E1i) {
    int tid = threadIdx.x;
    int w = tid >> 6, l = tid & 63;
    int rowglob = blockIdx.x * 4 + w;          // b*TN + m
    int b = rowglob >> 12;
    int m = rowglob & (TN - 1);
    const float* src = (m < NN) ? (ht + ((size_t)b * NN + m) * DD)
                                : (h  + ((size_t)b * NN + (m - NN)) * DD);
    const f32x4* src4 = reinterpret_cast<const f32x4*>(src);
    float c0 = 0.f, c1 = 0.f, c2 = 0.f, c3 = 0.f;
    #pragma unroll
    for (int k = 0; k < 16; ++k) {
        f32x4 s = src4[k];                      // wave-uniform 16B broadcast
        c0 += s[0] * W[(k * 4 + 0) * 64 + l];
        c1 += s[1] * W[(k * 4 + 1) * 64 + l];
        c2 += s[2] * W[(k * 4 + 2) * 64 + l];
        c3 += s[3] * W[(k * 4 + 3) * 64 + l];
    }
    float acc = (c0 + c1) + (c2 + c3);
    Wh[((size_t)b * TN + m) * DD + l] = acc;
    float r1 = acc * a1[l];
    float r2 = acc * a2[l];
    #pragma unroll
    for (int off = 32; off > 0; off >>= 1) {
        r1 += __shfl_xor(r1, off, 64);
        r2 += __shfl_xor(r2, off, 64);
    }
    if (l == 0) {
        size_t o = (size_t)b * TN + m;
        float pp = __expf(r1), pn = __expf(0.2f * r1);
        E1p[o] = pp;
        E1n[o] = pn;
        // interleaved: [0..3]=p(b0..3) [4..7]=n(b0..3) [8..11]=p(b4..7) [12..15]=n(b4..7)
        int sp = (b < 4) ? b       : 8 + (b - 4);
        int sn = (b < 4) ? 4 + b   : 12 + (b - 4);
        E1i[(size_t)m * 16 + sp] = pp;
        E1i[(size_t)m * 16 + sn] = pn;
        E2p[o] = __expf(r2);
        E2n[o] = __expf(0.2f * r2);
    }
}

// K2 (fused mask+stats): one streaming pass over adj (64 MB).
// e1 via wave-uniform f32x4 loads (no LDS); masking via acc += v*av (adj in {0,1});
// packed-f32 math across 4-batch groups. grid (16 j-tiles x 64 i-strips).
__global__ __launch_bounds__(256) void k2_mask_stats(
    const float* __restrict__ adj,
    const float* __restrict__ E1i,
    const float* __restrict__ E2p, const float* __restrict__ E2n,
    unsigned long long* __restrict__ rowmask,
    float* __restrict__ Spart) {
    int tid = threadIdx.x;
    int w = tid >> 6, l = tid & 63;
    int j = blockIdx.x * 256 + tid;
    int i0 = blockIdx.y * 64;
    f32x4 e2p0, e2p1, e2n0, e2n1;
    #pragma unroll
    for (int b = 0; b < 4; ++b) {
        e2p0[b] = E2p[(size_t)b * TN + j];
        e2n0[b] = E2n[(size_t)b * TN + j];
        e2p1[b] = E2p[(size_t)(b + 4) * TN + j];
        e2n1[b] = E2n[(size_t)(b + 4) * TN + j];
    }
    f32x4 acc0 = {0.f, 0.f, 0.f, 0.f}, acc1 = {0.f, 0.f, 0.f, 0.f};
    const f32x4* e1 = reinterpret_cast<const f32x4*>(E1i + (size_t)i0 * 16);
    #pragma unroll 4
    for (int ii = 0; ii < 64; ++ii) {
        float av = adj[(size_t)(i0 + ii) * TN + j];     // coalesced 256B/wave
        unsigned long long bal = __ballot(av != 0.f);
        if (l == 0)
            rowmask[(size_t)(i0 + ii) * 64 + blockIdx.x * 4 + w] = bal;
        f32x4 P0 = e1[ii * 4 + 0];                      // wave-uniform loads
        f32x4 N0 = e1[ii * 4 + 1];
        f32x4 P1 = e1[ii * 4 + 2];
        f32x4 N1 = e1[ii * 4 + 3];
        f32x4 v0 = __builtin_elementwise_max(P0 * e2p0, N0 * e2n0);
        f32x4 v1 = __builtin_elementwise_max(P1 * e2p1, N1 * e2n1);
        acc0 += v0 * av;                                 // av in {0,1}: exact mask
        acc1 += v1 * av;
    }
    #pragma unroll
    for (int b = 0; b < 4; ++b) {
        Spart[((size_t)blockIdx.y * 8 + b) * TN + j]     = acc0[b];
        Spart[((size_t)blockIdx.y * 8 + b + 4) * TN + j] = acc1[b];
    }
}

// K3: reduce Spart -> 1/S, then Whn_t[b][d][j] = Wh[b][j][d]/S[b][j] (bf16 T)
__global__ __launch_bounds__(256) void k3_whn(
    const float* __restrict__ Wh,
    const float* __restrict__ Spart,
    unsigned short* __restrict__ Wt) {
    __shared__ float tile[64][65];
    __shared__ float ps[4][64];
    __shared__ float rs[64];
    int b = blockIdx.y;
    int j0 = blockIdx.x * 64;
    int tid = threadIdx.x;
    int jj = tid & 63, part = tid >> 6;
    float s = 0.f;
    #pragma unroll
    for (int k = 0; k < 16; ++k) {
        int is = part * 16 + k;
        s += Spart[((size_t)is * 8 + b) * TN + j0 + jj];
    }
    ps[part][jj] = s;
    __syncthreads();
    if (tid < 64) rs[tid] = 1.0f / (ps[0][tid] + ps[1][tid] + ps[2][tid] + ps[3][tid]);
    for (int e = tid; e < 4096; e += 256) {
        int jt = e >> 6, d = e & 63;
        tile[jt][d] = Wh[((size_t)b * TN + j0 + jt) * DD + d];
    }
    __syncthreads();
    for (int e = tid; e < 512; e += 256) {
        int d = e >> 3, jg = e & 7;
        union { unsigned short u[8]; short8 s8; } pk;
        #pragma unroll
        for (int k = 0; k < 8; ++k) {
            int jt = jg * 8 + k;
            pk.u[k] = f2bf(tile[jt][d] * rs[jt]);
        }
        *reinterpret_cast<short8*>(Wt + ((size_t)b * DD + d) * TN + j0 + jg * 8) = pk.s8;
    }
}

// K4: hp_js[i][d] = sum_{j in quarter} P[i][j]*Whn[j][d]; P on the fly in MFMA
// A-layout. 256 thr (4 waves), i-tile 64, js=4 -> grid 2048 = 8 blocks/CU
// (LDS 17.9 KB x 8 = 143 KB; 32 waves/CU). Single-buffer LDS B-tile (stride 140),
// 2-barrier jt loop with register prefetch. Plain bf16 stores to per-js buffer.
__global__ __launch_bounds__(256, 8) void k4_pv(
    const unsigned int* __restrict__ rowmask32,
    const float* __restrict__ E1p, const float* __restrict__ E1n,
    const float* __restrict__ E2p, const float* __restrict__ E2n,
    const unsigned short* __restrict__ Wt,
    unsigned short* __restrict__ hpq) {
    __shared__ unsigned short wt_s[64 * 140];
    int bx = blockIdx.x;
    int b  = bx & 7;                 // XCD round-robin
    int js = (bx >> 3) & 3;
    int i0 = (bx >> 5) * 64;
    int tid = threadIdx.x;
    int w = tid >> 6, l = tid & 63;
    int m = l & 15, q = l >> 4;
    int irow = i0 + w * 16 + m;
    float e1p_v = E1p[(size_t)b * TN + irow];
    float e1n_v = E1n[(size_t)b * TN + irow];
    const float* e2pb = E2p + (size_t)b * TN;
    const float* e2nb = E2n + (size_t)b * TN;
    const unsigned short* wtb = Wt + (size_t)b * DD * TN;
    const unsigned int* mrow = rowmask32 + (size_t)irow * 128;

    int r0 = tid >> 4, c0 = tid & 15;
    const int jbase = js * 1024;

    f32x4 acc[4];
    #pragma unroll
    for (int dt = 0; dt < 4; ++dt) acc[dt] = (f32x4){0.f, 0.f, 0.f, 0.f};

    // prefetch tile jt=0
    short8 g[4];
    #pragma unroll
    for (int k = 0; k < 4; ++k)
        g[k] = *reinterpret_cast<const short8*>(
            wtb + (size_t)(r0 + 16 * k) * TN + jbase + c0 * 8);

    for (int jt = 0; jt < 8; ++jt) {
        int j0 = jbase + jt * 128;
        __syncthreads();                                  // prior reads done
        #pragma unroll
        for (int k = 0; k < 4; ++k)
            *reinterpret_cast<short8*>(&wt_s[(r0 + 16 * k) * 140 + c0 * 8]) = g[k];
        if (jt < 7) {                                     // prefetch next tile
            #pragma unroll
            for (int k = 0; k < 4; ++k)
                g[k] = *reinterpret_cast<const short8*>(
                    wtb + (size_t)(r0 + 16 * k) * TN + j0 + 128 + c0 * 8);
        }
        u32x4 m4 = *reinterpret_cast<const u32x4*>(mrow + (j0 >> 5));
        __syncthreads();                                  // tile visible

        #pragma unroll
        for (int t = 0; t < 4; ++t) {
            int jb = j0 + t * 32 + q * 8;
            unsigned int bytev = (m4[t] >> (q * 8)) & 0xFFu;
            f32x4 p20 = *reinterpret_cast<const f32x4*>(e2pb + jb);
            f32x4 p21 = *reinterpret_cast<const f32x4*>(e2pb + jb + 4);
            f32x4 n20 = *reinterpret_cast<const f32x4*>(e2nb + jb);
            f32x4 n21 = *reinterpret_cast<const f32x4*>(e2nb + jb + 4);
            f32x4 v0 = __builtin_elementwise_max(p20 * e1p_v, n20 * e1n_v);
            f32x4 v1 = __builtin_elementwise_max(p21 * e1p_v, n21 * e1n_v);
            union { f32x4 f; u32x4 u; } uv0, uv1;
            uv0.f = v0; uv1.f = v1;
            u32x4 mk0, mk1;
            #pragma unroll
            for (int c = 0; c < 4; ++c) {
                mk0[c] = (unsigned int)((int)(bytev << (31 - c)) >> 31);
                mk1[c] = (unsigned int)((int)(bytev << (27 - c)) >> 31);
            }
            uv0.u &= mk0; uv1.u &= mk1;
            union { unsigned int u[4]; short8 s8; } af;
            __hip_bfloat162 hb0 = __float22bfloat162_rn(make_float2(uv0.f[0], uv0.f[1]));
            __hip_bfloat162 hb1 = __float22bfloat162_rn(make_float2(uv0.f[2], uv0.f[3]));
            __hip_bfloat162 hb2 = __float22bfloat162_rn(make_float2(uv1.f[0], uv1.f[1]));
            __hip_bfloat162 hb3 = __float22bfloat162_rn(make_float2(uv1.f[2], uv1.f[3]));
            af.u[0] = *reinterpret_cast<unsigned int*>(&hb0);
            af.u[1] = *reinterpret_cast<unsigned int*>(&hb1);
            af.u[2] = *reinterpret_cast<unsigned int*>(&hb2);
            af.u[3] = *reinterpret_cast<unsigned int*>(&hb3);
            #pragma unroll
            for (int dt = 0; dt < 4; ++dt) {
                short8 bf = *reinterpret_cast<const short8*>(
                    &wt_s[(dt * 16 + m) * 140 + t * 32 + q * 8]);
                acc[dt] = __builtin_amdgcn_mfma_f32_16x16x32_bf16(af.s8, bf, acc[dt], 0, 0, 0);
            }
        }
    }

    // C row = q*4+r, col = dt*16+m; plain bf16 stores, disjoint per (js,b,i,d)
    unsigned short* hp = hpq + (size_t)js * (BB * (size_t)TN * DD);
    int gbase = i0 + w * 16 + q * 4;
    #pragma unroll
    for (int dt = 0; dt < 4; ++dt) {
        int d = dt * 16 + m;
        #pragma unroll
        for (int r = 0; r < 4; ++r) {
            int g2 = gbase + r;
            hp[((size_t)b * TN + g2) * DD + d] = f2bf(acc[dt][r]);
        }
    }
}

// K5: out = elu(sum_js hp[js]) with concat remap; bf16 partial reads, f32 store
__global__ void k5_epi(const unsigned short* __restrict__ hpq,
                       float* __restrict__ out) {
    int t = blockIdx.x * 256 + threadIdx.x;       // < 524288
    int d4 = t & 31;
    int n = (t >> 5) & 2047;
    int b = t >> 16;
    int g, sd;
    if (d4 < 16) { g = n;        sd = d4 * 4; }
    else         { g = n + NN;   sd = (d4 - 16) * 4; }
    size_t off = ((size_t)b * TN + g) * DD + sd;
    const size_t stride = (size_t)BB * TN * DD;
    f32x4 s = {0.f, 0.f, 0.f, 0.f};
    #pragma unroll
    for (int js = 0; js < 4; ++js) {
        u16x4 p = *reinterpret_cast<const u16x4*>(hpq + js * stride + off);
        #pragma unroll
        for (int c = 0; c < 4; ++c) s[c] += bf2f(p[c]);
    }
    f32x4 r;
    #pragma unroll
    for (int c = 0; c < 4; ++c) r[c] = (s[c] > 0.f) ? s[c] : expm1f(s[c]);
    *reinterpret_cast<f32x4*>(out + ((size_t)b * NN + n) * 128 + d4 * 4) = r;
}

extern "C" void kernel_launch(void* const* d_in, const int* in_sizes, int n_in,
                              void* d_out, int out_size, void* d_ws, size_t ws_size,
                              hipStream_t stream) {
    const float* h   = (const float*)d_in[0];
    const float* ht  = (const float*)d_in[1];
    const float* W   = (const float*)d_in[2];
    const float* a1  = (const float*)d_in[3];
    const float* a2  = (const float*)d_in[4];
    const float* adj = (const float*)d_in[5];
    float* out = (float*)d_out;

    char* ws = (char*)d_ws;
    float* Wh          = (float*)(ws);                       // 8 MB
    float* Spart       = (float*)(ws + (8 << 20));           // 8 MB
    unsigned short* Wt = (unsigned short*)(ws + (16 << 20)); // 4 MB
    float* E1p         = (float*)(ws + (20 << 20));
    float* E1n         = (float*)(ws + (20 << 20) + (128 << 10));
    float* E2p         = (float*)(ws + (20 << 20) + (256 << 10));
    float* E2n         = (float*)(ws + (20 << 20) + (384 << 10));
    unsigned long long* rowmask = (unsigned long long*)(ws + (20 << 20) + (512 << 10)); // 2 MB
    float* E1i         = (float*)(ws + (20 << 20) + (512 << 10) + (2 << 20)); // 256 KB
    const unsigned int* rowmask32 = (const unsigned int*)rowmask;
    // 4 bf16 partial buffers (4 MB each) overlay Wh+Spart (dead after k3)
    unsigned short* hpq = (unsigned short*)ws;               // 16 MB total

    k1_wh<<<dim3(BB * TN / 4), dim3(256), 0, stream>>>(h, ht, W, a1, a2, Wh,
                                                       E1p, E1n, E2p, E2n, E1i);
    k2_mask_stats<<<dim3(16, 64), dim3(256), 0, stream>>>(adj, E1i, E2p, E2n,
                                                          rowmask, Spart);
    k3_whn<<<dim3(64, 8), dim3(256), 0, stream>>>(Wh, Spart, Wt);
    k4_pv<<<dim3(2048), dim3(256), 0, stream>>>(rowmask32, E1p, E1n, E2p, E2n, Wt,
                                                hpq);
    k5_epi<<<dim3(2048), dim3(256), 0, stream>>>(hpq, out);
}

// Round 11
// 272.843 us; speedup vs baseline: 1.0911x; 1.0410x over previous
//
#include <hip/hip_runtime.h>
#include <hip/hip_bf16.h>
#include <math.h>

#define BB 8
#define NN 2048
#define TN 4096
#define DD 64

typedef __attribute__((ext_vector_type(8))) short short8;
typedef __attribute__((ext_vector_type(4))) float f32x4;
typedef __attribute__((ext_vector_type(4))) unsigned int u32x4;

__device__ __forceinline__ unsigned short f2bf(float f) {
    union { float f; unsigned int i; } v; v.f = f;
    unsigned int r = v.i + 0x7FFF + ((v.i >> 16) & 1);   // RNE
    return (unsigned short)(r >> 16);
}
__device__ __forceinline__ float bf2f(unsigned short u) {
    union { unsigned int i; float f; } v; v.i = ((unsigned int)u) << 16; return v.f;
}

// K1: Wh = concat(ht,h) @ W (f32); s1 = Wh@a1, s2 = Wh@a2; exp tables.
__global__ void k1_wh(const float* __restrict__ h,
                      const float* __restrict__ ht,
                      const float* __restrict__ W,
                      const float* __restrict__ a1,
                      const float* __restrict__ a2,
                      float* __restrict__ Wh,
                      float* __restrict__ E1p, float* __restrict__ E1n,
                      float* __restrict__ E2p, float* __restrict__ E2n,
                      float* __restrict__ E1i) {
    int tid = threadIdx.x;
    int w = tid >> 6, l = tid & 63;
    int rowglob = blockIdx.x * 4 + w;          // b*TN + m
    int b = rowglob >> 12;
    int m = rowglob & (TN - 1);
    const float* src = (m < NN) ? (ht + ((size_t)b * NN + m) * DD)
                                : (h  + ((size_t)b * NN + (m - NN)) * DD);
    const f32x4* src4 = reinterpret_cast<const f32x4*>(src);
    float c0 = 0.f, c1 = 0.f, c2 = 0.f, c3 = 0.f;
    #pragma unroll
    for (int k = 0; k < 16; ++k) {
        f32x4 s = src4[k];                      // wave-uniform 16B broadcast
        c0 += s[0] * W[(k * 4 + 0) * 64 + l];
        c1 += s[1] * W[(k * 4 + 1) * 64 + l];
        c2 += s[2] * W[(k * 4 + 2) * 64 + l];
        c3 += s[3] * W[(k * 4 + 3) * 64 + l];
    }
    float acc = (c0 + c1) + (c2 + c3);
    Wh[((size_t)b * TN + m) * DD + l] = acc;
    float r1 = acc * a1[l];
    float r2 = acc * a2[l];
    #pragma unroll
    for (int off = 32; off > 0; off >>= 1) {
        r1 += __shfl_xor(r1, off, 64);
        r2 += __shfl_xor(r2, off, 64);
    }
    if (l == 0) {
        size_t o = (size_t)b * TN + m;
        float pp = __expf(r1), pn = __expf(0.2f * r1);
        E1p[o] = pp;
        E1n[o] = pn;
        int sp = (b < 4) ? b       : 8 + (b - 4);
        int sn = (b < 4) ? 4 + b   : 12 + (b - 4);
        E1i[(size_t)m * 16 + sp] = pp;
        E1i[(size_t)m * 16 + sn] = pn;
        E2p[o] = __expf(r2);
        E2n[o] = __expf(0.2f * r2);
    }
}

// K2 (fused mask+stats): one streaming pass over adj (64 MB).
__global__ __launch_bounds__(256) void k2_mask_stats(
    const float* __restrict__ adj,
    const float* __restrict__ E1i,
    const float* __restrict__ E2p, const float* __restrict__ E2n,
    unsigned long long* __restrict__ rowmask,
    float* __restrict__ Spart) {
    int tid = threadIdx.x;
    int w = tid >> 6, l = tid & 63;
    int j = blockIdx.x * 256 + tid;
    int i0 = blockIdx.y * 64;
    f32x4 e2p0, e2p1, e2n0, e2n1;
    #pragma unroll
    for (int b = 0; b < 4; ++b) {
        e2p0[b] = E2p[(size_t)b * TN + j];
        e2n0[b] = E2n[(size_t)b * TN + j];
        e2p1[b] = E2p[(size_t)(b + 4) * TN + j];
        e2n1[b] = E2n[(size_t)(b + 4) * TN + j];
    }
    f32x4 acc0 = {0.f, 0.f, 0.f, 0.f}, acc1 = {0.f, 0.f, 0.f, 0.f};
    const f32x4* e1 = reinterpret_cast<const f32x4*>(E1i + (size_t)i0 * 16);
    #pragma unroll 4
    for (int ii = 0; ii < 64; ++ii) {
        float av = adj[(size_t)(i0 + ii) * TN + j];     // coalesced 256B/wave
        unsigned long long bal = __ballot(av != 0.f);
        if (l == 0)
            rowmask[(size_t)(i0 + ii) * 64 + blockIdx.x * 4 + w] = bal;
        f32x4 P0 = e1[ii * 4 + 0];                      // wave-uniform loads
        f32x4 N0 = e1[ii * 4 + 1];
        f32x4 P1 = e1[ii * 4 + 2];
        f32x4 N1 = e1[ii * 4 + 3];
        f32x4 v0 = __builtin_elementwise_max(P0 * e2p0, N0 * e2n0);
        f32x4 v1 = __builtin_elementwise_max(P1 * e2p1, N1 * e2n1);
        acc0 += v0 * av;                                 // av in {0,1}: exact mask
        acc1 += v1 * av;
    }
    #pragma unroll
    for (int b = 0; b < 4; ++b) {
        Spart[((size_t)blockIdx.y * 8 + b) * TN + j]     = acc0[b];
        Spart[((size_t)blockIdx.y * 8 + b + 4) * TN + j] = acc1[b];
    }
}

// K3: reduce Spart -> 1/S, then Whn_t[b][d][j] = Wh[b][j][d]/S[b][j] (bf16 T)
__global__ __launch_bounds__(256) void k3_whn(
    const float* __restrict__ Wh,
    const float* __restrict__ Spart,
    unsigned short* __restrict__ Wt) {
    __shared__ float tile[64][65];
    __shared__ float ps[4][64];
    __shared__ float rs[64];
    int b = blockIdx.y;
    int j0 = blockIdx.x * 64;
    int tid = threadIdx.x;
    int jj = tid & 63, part = tid >> 6;
    float s = 0.f;
    #pragma unroll
    for (int k = 0; k < 16; ++k) {
        int is = part * 16 + k;
        s += Spart[((size_t)is * 8 + b) * TN + j0 + jj];
    }
    ps[part][jj] = s;
    __syncthreads();
    if (tid < 64) rs[tid] = 1.0f / (ps[0][tid] + ps[1][tid] + ps[2][tid] + ps[3][tid]);
    for (int e = tid; e < 4096; e += 256) {
        int jt = e >> 6, d = e & 63;
        tile[jt][d] = Wh[((size_t)b * TN + j0 + jt) * DD + d];
    }
    __syncthreads();
    for (int e = tid; e < 512; e += 256) {
        int d = e >> 3, jg = e & 7;
        union { unsigned short u[8]; short8 s8; } pk;
        #pragma unroll
        for (int k = 0; k < 8; ++k) {
            int jt = jg * 8 + k;
            pk.u[k] = f2bf(tile[jt][d] * rs[jt]);
        }
        *reinterpret_cast<short8*>(Wt + ((size_t)b * DD + d) * TN + j0 + jg * 8) = pk.s8;
    }
}

// K4: hp partials, P on the fly in MFMA A-layout. 256 thr (4 waves), i-tile 64,
// js=4 -> grid 2048 = 8 blocks/CU. Single-buffer LDS B-tile (stride 140).
// Epilogue: MFMA-native per-lane bf16 layout -> 2x dwordx4/lane, wave = 2 KB
// contiguous (full sectors, no RMW). k5 unpermutes.
__global__ __launch_bounds__(256, 8) void k4_pv(
    const unsigned int* __restrict__ rowmask32,
    const float* __restrict__ E1p, const float* __restrict__ E1n,
    const float* __restrict__ E2p, const float* __restrict__ E2n,
    const unsigned short* __restrict__ Wt,
    unsigned short* __restrict__ hpq) {
    __shared__ unsigned short wt_s[64 * 140];
    int bx = blockIdx.x;
    int b  = bx & 7;                 // XCD round-robin
    int js = (bx >> 3) & 3;
    int it = bx >> 5;                // i-tile index 0..63
    int i0 = it * 64;
    int tid = threadIdx.x;
    int w = tid >> 6, l = tid & 63;
    int m = l & 15, q = l >> 4;
    int irow = i0 + w * 16 + m;
    float e1p_v = E1p[(size_t)b * TN + irow];
    float e1n_v = E1n[(size_t)b * TN + irow];
    const float* e2pb = E2p + (size_t)b * TN;
    const float* e2nb = E2n + (size_t)b * TN;
    const unsigned short* wtb = Wt + (size_t)b * DD * TN;
    const unsigned int* mrow = rowmask32 + (size_t)irow * 128;

    int r0 = tid >> 4, c0 = tid & 15;
    const int jbase = js * 1024;

    f32x4 acc[4];
    #pragma unroll
    for (int dt = 0; dt < 4; ++dt) acc[dt] = (f32x4){0.f, 0.f, 0.f, 0.f};

    // prefetch tile jt=0
    short8 g[4];
    #pragma unroll
    for (int k = 0; k < 4; ++k)
        g[k] = *reinterpret_cast<const short8*>(
            wtb + (size_t)(r0 + 16 * k) * TN + jbase + c0 * 8);

    for (int jt = 0; jt < 8; ++jt) {
        int j0 = jbase + jt * 128;
        __syncthreads();                                  // prior reads done
        #pragma unroll
        for (int k = 0; k < 4; ++k)
            *reinterpret_cast<short8*>(&wt_s[(r0 + 16 * k) * 140 + c0 * 8]) = g[k];
        if (jt < 7) {                                     // prefetch next tile
            #pragma unroll
            for (int k = 0; k < 4; ++k)
                g[k] = *reinterpret_cast<const short8*>(
                    wtb + (size_t)(r0 + 16 * k) * TN + j0 + 128 + c0 * 8);
        }
        u32x4 m4 = *reinterpret_cast<const u32x4*>(mrow + (j0 >> 5));
        __syncthreads();                                  // tile visible

        #pragma unroll
        for (int t = 0; t < 4; ++t) {
            int jb = j0 + t * 32 + q * 8;
            unsigned int bytev = (m4[t] >> (q * 8)) & 0xFFu;
            f32x4 p20 = *reinterpret_cast<const f32x4*>(e2pb + jb);
            f32x4 p21 = *reinterpret_cast<const f32x4*>(e2pb + jb + 4);
            f32x4 n20 = *reinterpret_cast<const f32x4*>(e2nb + jb);
            f32x4 n21 = *reinterpret_cast<const f32x4*>(e2nb + jb + 4);
            f32x4 v0 = __builtin_elementwise_max(p20 * e1p_v, n20 * e1n_v);
            f32x4 v1 = __builtin_elementwise_max(p21 * e1p_v, n21 * e1n_v);
            union { f32x4 f; u32x4 u; } uv0, uv1;
            uv0.f = v0; uv1.f = v1;
            u32x4 mk0, mk1;
            #pragma unroll
            for (int c = 0; c < 4; ++c) {
                mk0[c] = (unsigned int)((int)(bytev << (31 - c)) >> 31);
                mk1[c] = (unsigned int)((int)(bytev << (27 - c)) >> 31);
            }
            uv0.u &= mk0; uv1.u &= mk1;
            union { unsigned int u[4]; short8 s8; } af;
            __hip_bfloat162 hb0 = __float22bfloat162_rn(make_float2(uv0.f[0], uv0.f[1]));
            __hip_bfloat162 hb1 = __float22bfloat162_rn(make_float2(uv0.f[2], uv0.f[3]));
            __hip_bfloat162 hb2 = __float22bfloat162_rn(make_float2(uv1.f[0], uv1.f[1]));
            __hip_bfloat162 hb3 = __float22bfloat162_rn(make_float2(uv1.f[2], uv1.f[3]));
            af.u[0] = *reinterpret_cast<unsigned int*>(&hb0);
            af.u[1] = *reinterpret_cast<unsigned int*>(&hb1);
            af.u[2] = *reinterpret_cast<unsigned int*>(&hb2);
            af.u[3] = *reinterpret_cast<unsigned int*>(&hb3);
            #pragma unroll
            for (int dt = 0; dt < 4; ++dt) {
                short8 bf = *reinterpret_cast<const short8*>(
                    &wt_s[(dt * 16 + m) * 140 + t * 32 + q * 8]);
                acc[dt] = __builtin_amdgcn_mfma_f32_16x16x32_bf16(af.s8, bf, acc[dt], 0, 0, 0);
            }
        }
    }

    // Epilogue: lane-native layout. element (js,b,it,w,lane,k) with k=dt*4+r.
    // flat ushort idx = ((((js*8+b)*64+it)*4+w)*64 + l)*16 + k
    union { unsigned int u[8]; u32x4 v[2]; } pk;
    #pragma unroll
    for (int dt = 0; dt < 4; ++dt) {
        __hip_bfloat162 p0 = __float22bfloat162_rn(make_float2(acc[dt][0], acc[dt][1]));
        __hip_bfloat162 p1 = __float22bfloat162_rn(make_float2(acc[dt][2], acc[dt][3]));
        pk.u[dt * 2 + 0] = *reinterpret_cast<unsigned int*>(&p0);
        pk.u[dt * 2 + 1] = *reinterpret_cast<unsigned int*>(&p1);
    }
    unsigned short* hp = hpq +
        (((((size_t)js * 8 + b) * 64 + it) * 4 + w) * 64 + l) * 16;
    *reinterpret_cast<u32x4*>(hp)     = pk.v[0];
    *reinterpret_cast<u32x4*>(hp + 8) = pk.v[1];
}

// K5: out = elu(sum_js hp[js]) with concat remap + layout unpermute; f32 store.
__global__ void k5_epi(const unsigned short* __restrict__ hpq,
                       float* __restrict__ out) {
    int t = blockIdx.x * 256 + threadIdx.x;       // < 524288
    int d4 = t & 31;
    int n = (t >> 5) & 2047;
    int b = t >> 16;
    int g, sd;
    if (d4 < 16) { g = n;        sd = d4 * 4; }
    else         { g = n + NN;   sd = (d4 - 16) * 4; }
    int it = g >> 6, w = (g >> 4) & 3, q = (g >> 2) & 3, r = g & 3;
    int dt = sd >> 4, m0 = sd & 15;
    const size_t JSTR = (size_t)8 * 64 * 4 * 64 * 16;   // 2,097,152 ushorts / js
    size_t base = ((((size_t)b * 64 + it) * 4 + w) * 64 + q * 16) * 16 + dt * 4 + r;
    f32x4 s = {0.f, 0.f, 0.f, 0.f};
    #pragma unroll
    for (int js = 0; js < 4; ++js) {
        const unsigned short* p = hpq + js * JSTR + base;
        #pragma unroll
        for (int c = 0; c < 4; ++c) s[c] += bf2f(p[(size_t)(m0 + c) * 16]);
    }
    f32x4 rr;
    #pragma unroll
    for (int c = 0; c < 4; ++c) rr[c] = (s[c] > 0.f) ? s[c] : expm1f(s[c]);
    *reinterpret_cast<f32x4*>(out + ((size_t)b * NN + n) * 128 + d4 * 4) = rr;
}

extern "C" void kernel_launch(void* const* d_in, const int* in_sizes, int n_in,
                              void* d_out, int out_size, void* d_ws, size_t ws_size,
                              hipStream_t stream) {
    const float* h   = (const float*)d_in[0];
    const float* ht  = (const float*)d_in[1];
    const float* W   = (const float*)d_in[2];
    const float* a1  = (const float*)d_in[3];
    const float* a2  = (const float*)d_in[4];
    const float* adj = (const float*)d_in[5];
    float* out = (float*)d_out;

    char* ws = (char*)d_ws;
    float* Wh          = (float*)(ws);                       // 8 MB
    float* Spart       = (float*)(ws + (8 << 20));           // 8 MB
    unsigned short* Wt = (unsigned short*)(ws + (16 << 20)); // 4 MB
    float* E1p         = (float*)(ws + (20 << 20));
    float* E1n         = (float*)(ws + (20 << 20) + (128 << 10));
    float* E2p         = (float*)(ws + (20 << 20) + (256 << 10));
    float* E2n         = (float*)(ws + (20 << 20) + (384 << 10));
    unsigned long long* rowmask = (unsigned long long*)(ws + (20 << 20) + (512 << 10)); // 2 MB
    float* E1i         = (float*)(ws + (20 << 20) + (512 << 10) + (2 << 20)); // 256 KB
    const unsigned int* rowmask32 = (const unsigned int*)rowmask;
    // 4 bf16 partial buffers (4 MB each, lane-native layout) overlay Wh+Spart
    unsigned short* hpq = (unsigned short*)ws;               // 16 MB total

    k1_wh<<<dim3(BB * TN / 4), dim3(256), 0, stream>>>(h, ht, W, a1, a2, Wh,
                                                       E1p, E1n, E2p, E2n, E1i);
    k2_mask_stats<<<dim3(16, 64), dim3(256), 0, stream>>>(adj, E1i, E2p, E2n,
                                                          rowmask, Spart);
    k3_whn<<<dim3(64, 8), dim3(256), 0, stream>>>(Wh, Spart, Wt);
    k4_pv<<<dim3(2048), dim3(256), 0, stream>>>(rowmask32, E1p, E1n, E2p, E2n, Wt,
                                                hpq);
    k5_epi<<<dim3(2048), dim3(256), 0, stream>>>(hpq, out);
}

// Round 12
// 242.878 us; speedup vs baseline: 1.2257x; 1.1234x over previous
//
#include <hip/hip_runtime.h>
#include <hip/hip_bf16.h>
#include <math.h>

#define BB 8
#define NN 2048
#define TN 4096
#define DD 64

typedef __attribute__((ext_vector_type(8))) short short8;
typedef __attribute__((ext_vector_type(4))) float f32x4;
typedef __attribute__((ext_vector_type(4))) unsigned int u32x4;

__device__ __forceinline__ unsigned short f2bf(float f) {
    union { float f; unsigned int i; } v; v.f = f;
    unsigned int r = v.i + 0x7FFF + ((v.i >> 16) & 1);   // RNE
    return (unsigned short)(r >> 16);
}
__device__ __forceinline__ float bf2f(unsigned short u) {
    union { unsigned int i; float f; } v; v.i = ((unsigned int)u) << 16; return v.f;
}

// K1: Wh = concat(ht,h) @ W (f32); s1 = Wh@a1, s2 = Wh@a2; exp tables.
__global__ void k1_wh(const float* __restrict__ h,
                      const float* __restrict__ ht,
                      const float* __restrict__ W,
                      const float* __restrict__ a1,
                      const float* __restrict__ a2,
                      float* __restrict__ Wh,
                      float* __restrict__ E1p, float* __restrict__ E1n,
                      float* __restrict__ E2p, float* __restrict__ E2n,
                      float* __restrict__ E1i) {
    int tid = threadIdx.x;
    int w = tid >> 6, l = tid & 63;
    int rowglob = blockIdx.x * 4 + w;          // b*TN + m
    int b = rowglob >> 12;
    int m = rowglob & (TN - 1);
    const float* src = (m < NN) ? (ht + ((size_t)b * NN + m) * DD)
                                : (h  + ((size_t)b * NN + (m - NN)) * DD);
    const f32x4* src4 = reinterpret_cast<const f32x4*>(src);
    float c0 = 0.f, c1 = 0.f, c2 = 0.f, c3 = 0.f;
    #pragma unroll
    for (int k = 0; k < 16; ++k) {
        f32x4 s = src4[k];                      // wave-uniform 16B broadcast
        c0 += s[0] * W[(k * 4 + 0) * 64 + l];
        c1 += s[1] * W[(k * 4 + 1) * 64 + l];
        c2 += s[2] * W[(k * 4 + 2) * 64 + l];
        c3 += s[3] * W[(k * 4 + 3) * 64 + l];
    }
    float acc = (c0 + c1) + (c2 + c3);
    Wh[((size_t)b * TN + m) * DD + l] = acc;
    float r1 = acc * a1[l];
    float r2 = acc * a2[l];
    #pragma unroll
    for (int off = 32; off > 0; off >>= 1) {
        r1 += __shfl_xor(r1, off, 64);
        r2 += __shfl_xor(r2, off, 64);
    }
    if (l == 0) {
        size_t o = (size_t)b * TN + m;
        float pp = __expf(r1), pn = __expf(0.2f * r1);
        E1p[o] = pp;
        E1n[o] = pn;
        int sp = (b < 4) ? b       : 8 + (b - 4);
        int sn = (b < 4) ? 4 + b   : 12 + (b - 4);
        E1i[(size_t)m * 16 + sp] = pp;
        E1i[(size_t)m * 16 + sn] = pn;
        E2p[o] = __expf(r2);
        E2n[o] = __expf(0.2f * r2);
    }
}

// K2 (fused mask+stats): one streaming pass over adj (64 MB).
__global__ __launch_bounds__(256) void k2_mask_stats(
    const float* __restrict__ adj,
    const float* __restrict__ E1i,
    const float* __restrict__ E2p, const float* __restrict__ E2n,
    unsigned long long* __restrict__ rowmask,
    float* __restrict__ Spart) {
    int tid = threadIdx.x;
    int w = tid >> 6, l = tid & 63;
    int j = blockIdx.x * 256 + tid;
    int i0 = blockIdx.y * 64;
    f32x4 e2p0, e2p1, e2n0, e2n1;
    #pragma unroll
    for (int b = 0; b < 4; ++b) {
        e2p0[b] = E2p[(size_t)b * TN + j];
        e2n0[b] = E2n[(size_t)b * TN + j];
        e2p1[b] = E2p[(size_t)(b + 4) * TN + j];
        e2n1[b] = E2n[(size_t)(b + 4) * TN + j];
    }
    f32x4 acc0 = {0.f, 0.f, 0.f, 0.f}, acc1 = {0.f, 0.f, 0.f, 0.f};
    const f32x4* e1 = reinterpret_cast<const f32x4*>(E1i + (size_t)i0 * 16);
    #pragma unroll 4
    for (int ii = 0; ii < 64; ++ii) {
        float av = adj[(size_t)(i0 + ii) * TN + j];     // coalesced 256B/wave
        unsigned long long bal = __ballot(av != 0.f);
        if (l == 0)
            rowmask[(size_t)(i0 + ii) * 64 + blockIdx.x * 4 + w] = bal;
        f32x4 P0 = e1[ii * 4 + 0];                      // wave-uniform loads
        f32x4 N0 = e1[ii * 4 + 1];
        f32x4 P1 = e1[ii * 4 + 2];
        f32x4 N1 = e1[ii * 4 + 3];
        f32x4 v0 = __builtin_elementwise_max(P0 * e2p0, N0 * e2n0);
        f32x4 v1 = __builtin_elementwise_max(P1 * e2p1, N1 * e2n1);
        acc0 += v0 * av;                                 // av in {0,1}: exact mask
        acc1 += v1 * av;
    }
    #pragma unroll
    for (int b = 0; b < 4; ++b) {
        Spart[((size_t)blockIdx.y * 8 + b) * TN + j]     = acc0[b];
        Spart[((size_t)blockIdx.y * 8 + b + 4) * TN + j] = acc1[b];
    }
}

// K3: reduce Spart -> 1/S, then Whn_t[b][d][j] = Wh[b][j][d]/S[b][j] (bf16 T)
__global__ __launch_bounds__(256) void k3_whn(
    const float* __restrict__ Wh,
    const float* __restrict__ Spart,
    unsigned short* __restrict__ Wt) {
    __shared__ float tile[64][65];
    __shared__ float ps[4][64];
    __shared__ float rs[64];
    int b = blockIdx.y;
    int j0 = blockIdx.x * 64;
    int tid = threadIdx.x;
    int jj = tid & 63, part = tid >> 6;
    float s = 0.f;
    #pragma unroll
    for (int k = 0; k < 16; ++k) {
        int is = part * 16 + k;
        s += Spart[((size_t)is * 8 + b) * TN + j0 + jj];
    }
    ps[part][jj] = s;
    __syncthreads();
    if (tid < 64) rs[tid] = 1.0f / (ps[0][tid] + ps[1][tid] + ps[2][tid] + ps[3][tid]);
    for (int e = tid; e < 4096; e += 256) {
        int jt = e >> 6, d = e & 63;
        tile[jt][d] = Wh[((size_t)b * TN + j0 + jt) * DD + d];
    }
    __syncthreads();
    for (int e = tid; e < 512; e += 256) {
        int d = e >> 3, jg = e & 7;
        union { unsigned short u[8]; short8 s8; } pk;
        #pragma unroll
        for (int k = 0; k < 8; ++k) {
            int jt = jg * 8 + k;
            pk.u[k] = f2bf(tile[jt][d] * rs[jt]);
        }
        *reinterpret_cast<short8*>(Wt + ((size_t)b * DD + d) * TN + j0 + jg * 8) = pk.s8;
    }
}

// K4: hp partials, P on the fly in MFMA A-layout. 256 thr (4 waves), i-tile 64,
// js=4 -> grid 2048. NO forced min-occupancy: __launch_bounds__(256,8) squeezed
// VGPR to 32 < live set -> scratch spills -> +110 MB HBM FETCH/WRITE (r9-r11).
// Compiler-chosen ~60 VGPR still allows 8 waves/SIMD (<=64 threshold).
__global__ __launch_bounds__(256) void k4_pv(
    const unsigned int* __restrict__ rowmask32,
    const float* __restrict__ E1p, const float* __restrict__ E1n,
    const float* __restrict__ E2p, const float* __restrict__ E2n,
    const unsigned short* __restrict__ Wt,
    unsigned short* __restrict__ hpq) {
    __shared__ unsigned short wt_s[64 * 140];
    int bx = blockIdx.x;
    int b  = bx & 7;                 // XCD round-robin
    int js = (bx >> 3) & 3;
    int it = bx >> 5;                // i-tile index 0..63
    int i0 = it * 64;
    int tid = threadIdx.x;
    int w = tid >> 6, l = tid & 63;
    int m = l & 15, q = l >> 4;
    int irow = i0 + w * 16 + m;
    float e1p_v = E1p[(size_t)b * TN + irow];
    float e1n_v = E1n[(size_t)b * TN + irow];
    const float* e2pb = E2p + (size_t)b * TN;
    const float* e2nb = E2n + (size_t)b * TN;
    const unsigned short* wtb = Wt + (size_t)b * DD * TN;
    const unsigned int* mrow = rowmask32 + (size_t)irow * 128;

    int r0 = tid >> 4, c0 = tid & 15;
    const int jbase = js * 1024;

    f32x4 acc[4];
    #pragma unroll
    for (int dt = 0; dt < 4; ++dt) acc[dt] = (f32x4){0.f, 0.f, 0.f, 0.f};

    // prefetch tile jt=0
    short8 g[4];
    #pragma unroll
    for (int k = 0; k < 4; ++k)
        g[k] = *reinterpret_cast<const short8*>(
            wtb + (size_t)(r0 + 16 * k) * TN + jbase + c0 * 8);

    for (int jt = 0; jt < 8; ++jt) {
        int j0 = jbase + jt * 128;
        __syncthreads();                                  // prior reads done
        #pragma unroll
        for (int k = 0; k < 4; ++k)
            *reinterpret_cast<short8*>(&wt_s[(r0 + 16 * k) * 140 + c0 * 8]) = g[k];
        if (jt < 7) {                                     // prefetch next tile
            #pragma unroll
            for (int k = 0; k < 4; ++k)
                g[k] = *reinterpret_cast<const short8*>(
                    wtb + (size_t)(r0 + 16 * k) * TN + j0 + 128 + c0 * 8);
        }
        u32x4 m4 = *reinterpret_cast<const u32x4*>(mrow + (j0 >> 5));
        __syncthreads();                                  // tile visible

        #pragma unroll
        for (int t = 0; t < 4; ++t) {
            int jb = j0 + t * 32 + q * 8;
            unsigned int bytev = (m4[t] >> (q * 8)) & 0xFFu;
            f32x4 p20 = *reinterpret_cast<const f32x4*>(e2pb + jb);
            f32x4 p21 = *reinterpret_cast<const f32x4*>(e2pb + jb + 4);
            f32x4 n20 = *reinterpret_cast<const f32x4*>(e2nb + jb);
            f32x4 n21 = *reinterpret_cast<const f32x4*>(e2nb + jb + 4);
            f32x4 v0 = __builtin_elementwise_max(p20 * e1p_v, n20 * e1n_v);
            f32x4 v1 = __builtin_elementwise_max(p21 * e1p_v, n21 * e1n_v);
            union { f32x4 f; u32x4 u; } uv0, uv1;
            uv0.f = v0; uv1.f = v1;
            u32x4 mk0, mk1;
            #pragma unroll
            for (int c = 0; c < 4; ++c) {
                mk0[c] = (unsigned int)((int)(bytev << (31 - c)) >> 31);
                mk1[c] = (unsigned int)((int)(bytev << (27 - c)) >> 31);
            }
            uv0.u &= mk0; uv1.u &= mk1;
            union { unsigned int u[4]; short8 s8; } af;
            __hip_bfloat162 hb0 = __float22bfloat162_rn(make_float2(uv0.f[0], uv0.f[1]));
            __hip_bfloat162 hb1 = __float22bfloat162_rn(make_float2(uv0.f[2], uv0.f[3]));
            __hip_bfloat162 hb2 = __float22bfloat162_rn(make_float2(uv1.f[0], uv1.f[1]));
            __hip_bfloat162 hb3 = __float22bfloat162_rn(make_float2(uv1.f[2], uv1.f[3]));
            af.u[0] = *reinterpret_cast<unsigned int*>(&hb0);
            af.u[1] = *reinterpret_cast<unsigned int*>(&hb1);
            af.u[2] = *reinterpret_cast<unsigned int*>(&hb2);
            af.u[3] = *reinterpret_cast<unsigned int*>(&hb3);
            #pragma unroll
            for (int dt = 0; dt < 4; ++dt) {
                short8 bf = *reinterpret_cast<const short8*>(
                    &wt_s[(dt * 16 + m) * 140 + t * 32 + q * 8]);
                acc[dt] = __builtin_amdgcn_mfma_f32_16x16x32_bf16(af.s8, bf, acc[dt], 0, 0, 0);
            }
        }
    }

    // Epilogue: lane-native layout. element (js,b,it,w,lane,k) with k=dt*4+r.
    // flat ushort idx = ((((js*8+b)*64+it)*4+w)*64 + l)*16 + k
    union { unsigned int u[8]; u32x4 v[2]; } pk;
    #pragma unroll
    for (int dt = 0; dt < 4; ++dt) {
        __hip_bfloat162 p0 = __float22bfloat162_rn(make_float2(acc[dt][0], acc[dt][1]));
        __hip_bfloat162 p1 = __float22bfloat162_rn(make_float2(acc[dt][2], acc[dt][3]));
        pk.u[dt * 2 + 0] = *reinterpret_cast<unsigned int*>(&p0);
        pk.u[dt * 2 + 1] = *reinterpret_cast<unsigned int*>(&p1);
    }
    unsigned short* hp = hpq +
        (((((size_t)js * 8 + b) * 64 + it) * 4 + w) * 64 + l) * 16;
    *reinterpret_cast<u32x4*>(hp)     = pk.v[0];
    *reinterpret_cast<u32x4*>(hp + 8) = pk.v[1];
}

// K5: out = elu(sum_js hp[js]) with concat remap + layout unpermute; f32 store.
__global__ void k5_epi(const unsigned short* __restrict__ hpq,
                       float* __restrict__ out) {
    int t = blockIdx.x * 256 + threadIdx.x;       // < 524288
    int d4 = t & 31;
    int n = (t >> 5) & 2047;
    int b = t >> 16;
    int g, sd;
    if (d4 < 16) { g = n;        sd = d4 * 4; }
    else         { g = n + NN;   sd = (d4 - 16) * 4; }
    int it = g >> 6, w = (g >> 4) & 3, q = (g >> 2) & 3, r = g & 3;
    int dt = sd >> 4, m0 = sd & 15;
    const size_t JSTR = (size_t)8 * 64 * 4 * 64 * 16;   // 2,097,152 ushorts / js
    size_t base = ((((size_t)b * 64 + it) * 4 + w) * 64 + q * 16) * 16 + dt * 4 + r;
    f32x4 s = {0.f, 0.f, 0.f, 0.f};
    #pragma unroll
    for (int js = 0; js < 4; ++js) {
        const unsigned short* p = hpq + js * JSTR + base;
        #pragma unroll
        for (int c = 0; c < 4; ++c) s[c] += bf2f(p[(size_t)(m0 + c) * 16]);
    }
    f32x4 rr;
    #pragma unroll
    for (int c = 0; c < 4; ++c) rr[c] = (s[c] > 0.f) ? s[c] : expm1f(s[c]);
    *reinterpret_cast<f32x4*>(out + ((size_t)b * NN + n) * 128 + d4 * 4) = rr;
}

extern "C" void kernel_launch(void* const* d_in, const int* in_sizes, int n_in,
                              void* d_out, int out_size, void* d_ws, size_t ws_size,
                              hipStream_t stream) {
    const float* h   = (const float*)d_in[0];
    const float* ht  = (const float*)d_in[1];
    const float* W   = (const float*)d_in[2];
    const float* a1  = (const float*)d_in[3];
    const float* a2  = (const float*)d_in[4];
    const float* adj = (const float*)d_in[5];
    float* out = (float*)d_out;

    char* ws = (char*)d_ws;
    float* Wh          = (float*)(ws);                       // 8 MB
    float* Spart       = (float*)(ws + (8 << 20));           // 8 MB
    unsigned short* Wt = (unsigned short*)(ws + (16 << 20)); // 4 MB
    float* E1p         = (float*)(ws + (20 << 20));
    float* E1n         = (float*)(ws + (20 << 20) + (128 << 10));
    float* E2p         = (float*)(ws + (20 << 20) + (256 << 10));
    float* E2n         = (float*)(ws + (20 << 20) + (384 << 10));
    unsigned long long* rowmask = (unsigned long long*)(ws + (20 << 20) + (512 << 10)); // 2 MB
    float* E1i         = (float*)(ws + (20 << 20) + (512 << 10) + (2 << 20)); // 256 KB
    const unsigned int* rowmask32 = (const unsigned int*)rowmask;
    // 4 bf16 partial buffers (4 MB each, lane-native layout) overlay Wh+Spart
    unsigned short* hpq = (unsigned short*)ws;               // 16 MB total

    k1_wh<<<dim3(BB * TN / 4), dim3(256), 0, stream>>>(h, ht, W, a1, a2, Wh,
                                                       E1p, E1n, E2p, E2n, E1i);
    k2_mask_stats<<<dim3(16, 64), dim3(256), 0, stream>>>(adj, E1i, E2p, E2n,
                                                          rowmask, Spart);
    k3_whn<<<dim3(64, 8), dim3(256), 0, stream>>>(Wh, Spart, Wt);
    k4_pv<<<dim3(2048), dim3(256), 0, stream>>>(rowmask32, E1p, E1n, E2p, E2n, Wt,
                                                hpq);
    k5_epi<<<dim3(2048), dim3(256), 0, stream>>>(hpq, out);
}